// Round 11
// baseline (781.690 us; speedup 1.0000x reference)
//
#include <hip/hip_runtime.h>
#include <cstddef>
#include <cstdint>

// Problem constants
#define BB   64
#define NN   512
#define BN   (BB*NN)          // 32768
#define HBN  16384            // nodes per half
#define EE   524288
#define DA   70
#define DE   14
#define DH   200
#define DI   6
#define T_SCALE 0.07071067811865475f   // sqrt(1/200)

typedef __attribute__((ext_vector_type(8))) short short8;
typedef __attribute__((ext_vector_type(4))) float f32x4;

__device__ __forceinline__ short f2bf(float x) {
    union { float f; unsigned u; } v; v.f = x;
    const unsigned r = v.u + 0x7FFFu + ((v.u >> 16) & 1u);   // RNE
    return (short)(r >> 16);
}
__device__ __forceinline__ float bf2f(short s) {
    union { unsigned u; float f; } v;
    v.u = ((unsigned)(unsigned short)s) << 16;
    return v.f;
}

// 16-lane (row) sum via DPP — pure VALU, no DS pipe, no address VGPRs.
__device__ __forceinline__ float dpp16_sum(float x) {
    union { float f; int i; } a, b;
    a.f = x;
    b.i = __builtin_amdgcn_update_dpp(0, a.i, 0xB1, 0xF, 0xF, false); a.f += b.f;
    b.i = __builtin_amdgcn_update_dpp(0, a.i, 0x4E, 0xF, 0xF, false); a.f += b.f;
    b.i = __builtin_amdgcn_update_dpp(0, a.i, 0x141, 0xF, 0xF, false); a.f += b.f;
    b.i = __builtin_amdgcn_update_dpp(0, a.i, 0x140, 0xF, 0xF, false); a.f += b.f;
    return a.f;
}

// ---------------------------------------------------------------------------
// prologue v3: HIST FIRST. Round-10 decomposition: hist's ~1M device-scope
// random atomics ~80-90us latency-bound, and they dispatched AFTER all node
// blocks -> serialized. Order now: hist [0,2048) -> its latency drains under
// the node compute [2048,6144). prep_w / prep_wt unchanged.
// ---------------------------------------------------------------------------
__global__ __launch_bounds__(256) void prologue_kernel(
    const float* __restrict__ atom1, const float* __restrict__ atom2,
    const float* __restrict__ W_atom,
    const float* __restrict__ ln_g, const float* __restrict__ ln_b,
    float* __restrict__ h1, float* __restrict__ h2,
    const int* __restrict__ edst1, const int* __restrict__ edst2,
    int* __restrict__ deg1, int* __restrict__ deg2,
    int* __restrict__ rank1, int* __restrict__ rank2,
    const float* __restrict__ W_edge, const float* __restrict__ W_rbf,
    const float* __restrict__ b_rbf,
    short* __restrict__ WTH, short* __restrict__ WTL,
    short* __restrict__ featH1, short* __restrict__ featH2,
    const float* __restrict__ W_down,
    short* __restrict__ WbTH, short* __restrict__ WbTL)
{
    const int bid = blockIdx.x;
    const int tid = threadIdx.x;

    if (bid < 2048) {
        // ---- hist phase (first: overlap atomic latency with node compute)
        const int e = bid*256 + tid;
        rank1[e] = atomicAdd(&deg1[edst1[e]], 1);
        rank2[e] = atomicAdd(&deg2[edst2[e]], 1);
        return;
    }

    if (bid < 6144) {
        // ---- node phase: 16 nodes per block
        const int nb = bid - 2048;
        const int side = nb >> 11;
        const float* atom = side ? atom2 : atom1;
        float* h = side ? h2 : h1;
        const int node0 = (nb & 2047) * 16;

        __shared__ float arow[16][72];    // padded rows -> 16B-aligned float4
        __shared__ float vals[16][DH];    // 12.8 KB

        for (int i = tid; i < 16*35; i += 256) {
            const int n = i / 35, k2 = i % 35;
            const float2 v = *(const float2*)&atom[(size_t)(node0+n)*DA + k2*2];
            arow[n][k2*2]   = v.x;
            arow[n][k2*2+1] = v.y;
        }
        if (tid < 32) arow[tid >> 1][70 + (tid & 1)] = 0.f;
        __syncthreads();

        if (tid < DH) {
            float a[16];
            #pragma unroll
            for (int n = 0; n < 16; n++) a[n] = 0.f;
            #pragma unroll 1
            for (int c4 = 0; c4 < 17; c4++) {
                const int k = c4*4;
                const float w0 = W_atom[(k+0)*DH + tid];
                const float w1 = W_atom[(k+1)*DH + tid];
                const float w2 = W_atom[(k+2)*DH + tid];
                const float w3 = W_atom[(k+3)*DH + tid];
                #pragma unroll
                for (int n = 0; n < 16; n++) {
                    const float4 av = *(const float4*)&arow[n][k];
                    a[n] += av.x*w0;
                    a[n] += av.y*w1;
                    a[n] += av.z*w2;
                    a[n] += av.w*w3;
                }
            }
            {   // tail k = 68, 69
                const float w0 = W_atom[68*DH + tid];
                const float w1 = W_atom[69*DH + tid];
                #pragma unroll
                for (int n = 0; n < 16; n++) {
                    a[n] += arow[n][68]*w0;
                    a[n] += arow[n][69]*w1;
                }
            }
            #pragma unroll
            for (int n = 0; n < 16; n++) vals[n][tid] = fmaxf(a[n], 0.f);
        }
        __syncthreads();

        const int wv = tid >> 6, lane = tid & 63;
        #pragma unroll 1
        for (int rr = 0; rr < 4; rr++) {
            const int n = rr*4 + wv;
            float v0 = vals[n][lane];
            float v1 = vals[n][64+lane];
            float v2 = vals[n][128+lane];
            float v3 = (lane < 8) ? vals[n][192+lane] : 0.0f;
            float s  = v0+v1+v2+v3;
            float s2 = v0*v0+v1*v1+v2*v2+v3*v3;
            #pragma unroll
            for (int off = 1; off < 64; off <<= 1) {
                s  += __shfl_xor(s,  off, 64);
                s2 += __shfl_xor(s2, off, 64);
            }
            const float mean = s * (1.0f/DH);
            const float var  = s2 * (1.0f/DH) - mean*mean;
            const float rstd = rsqrtf(var + 1e-5f);
            const size_t base = (size_t)(node0+n)*DH;
            h[base + lane]       = ln_g[lane]     *(v0-mean)*rstd + ln_b[lane];
            h[base + 64 + lane]  = ln_g[64+lane]  *(v1-mean)*rstd + ln_b[64+lane];
            h[base + 128 + lane] = ln_g[128+lane] *(v2-mean)*rstd + ln_b[128+lane];
            if (lane < 8)
                h[base + 192 + lane] = ln_g[192+lane]*(v3-mean)*rstd + ln_b[192+lane];
        }
        return;
    }

    if (bid < 6508) {
        // ---- prep_w phase
        const int idx = (bid - 6144)*256 + tid;
        if (idx >= 208*448) return;
        const int c = idx / 448, kk = idx - c*448;
        float v = 0.f;
        if (c < 200) {
            if (kk < 200) v = W_down[(size_t)kk*DH + c];
            else if (kk >= 224 && kk < 424) v = W_down[(size_t)(200 + kk - 224)*DH + c];
        }
        const short hi = f2bf(v);
        WbTH[idx] = hi;
        WbTL[idx] = f2bf(v - bf2f(hi));
        return;
    }

    // ---- prep_wt phase (26 blocks WT, 2 blocks feat pad)
    {
        const int pb = bid - 6508;
        if (pb >= 26) {
            short* f = (pb == 26) ? featH1 : featH2;
            f[(size_t)EE*32 + tid] = 0;
            f[(size_t)EE*32 + 256 + tid] = 0;
            return;
        }
        const int idx = pb*256 + tid;
        const int c = idx >> 5, k = idx & 31;
        float v = 0.f;
        if (c < 100) {
            if (k < 14) v = W_edge[k*100 + c];
        } else if (c < 200) {
            const int cc = c - 100;
            if (k >= 14 && k < 30) v = W_rbf[(k-14)*100 + cc];
            else if (k == 30) v = b_rbf[cc];
        }
        const short hi = f2bf(v);
        WTH[idx] = hi;
        WTL[idx] = f2bf(v - bf2f(hi));
    }
}

__global__ __launch_bounds__(1024) void scan_kernel(
    const int* __restrict__ deg1, const int* __restrict__ deg2,
    int* __restrict__ start1, int* __restrict__ start2)
{
    const int side = blockIdx.x;
    const int* deg   = side ? deg2 : deg1;
    int* start  = side ? start2 : start1;

    __shared__ int part[1024];
    const int t = threadIdx.x;
    const int base = t * 32;
    int local[32];
    int sum = 0;
    #pragma unroll
    for (int i = 0; i < 8; i++) {        // int4 vector loads (16B/lane)
        const int4 v = *(const int4*)&deg[base + i*4];
        local[4*i+0] = v.x; local[4*i+1] = v.y;
        local[4*i+2] = v.z; local[4*i+3] = v.w;
        sum += v.x + v.y + v.z + v.w;
    }
    part[t] = sum;
    __syncthreads();
    for (int off = 1; off < 1024; off <<= 1) {
        int v = (t >= off) ? part[t-off] : 0;
        __syncthreads();
        part[t] += v;
        __syncthreads();
    }
    int run = part[t] - sum;   // exclusive
    #pragma unroll
    for (int i = 0; i < 32; i++) {
        start[base+i] = run;
        run += local[i];
    }
    if (t == 1023) start[BN] = run;   // sentinel == EE
}

// ---------------------------------------------------------------------------
// featgen v2: float2 ef loads. Values bit-identical.
// ---------------------------------------------------------------------------
__global__ __launch_bounds__(256) void featgen_kernel(
    const float* __restrict__ efeat1, const float* __restrict__ efeat2,
    const int* __restrict__ esrc1, const int* __restrict__ esrc2,
    const int* __restrict__ edst1, const int* __restrict__ edst2,
    const float* __restrict__ coords1, const float* __restrict__ coords2,
    const int* __restrict__ rank1, const int* __restrict__ rank2,
    const int* __restrict__ start1, const int* __restrict__ start2,
    short* __restrict__ featH1, short* __restrict__ featH2)
{
    const int side = blockIdx.y;
    const float* ef     = side ? efeat2  : efeat1;
    const int*   esrc   = side ? esrc2   : esrc1;
    const int*   edst   = side ? edst2   : edst1;
    const float* coords = side ? coords2 : coords1;
    const int*   rank   = side ? rank2   : rank1;
    const int*   start  = side ? start2  : start1;
    short* featH = side ? featH2 : featH1;

    const int e = blockIdx.x*256 + threadIdx.x;
    const int src = esrc[e], dst = edst[e];

    float efv[14];
    #pragma unroll
    for (int q = 0; q < 7; q++) {
        const float2 v = *(const float2*)&ef[(size_t)e*DE + q*2];
        efv[2*q]   = v.x;
        efv[2*q+1] = v.y;
    }
    short f[32];
    #pragma unroll
    for (int k = 0; k < 14; k++) f[k] = f2bf(efv[k]);

    const float dx = coords[src*3+0] - coords[dst*3+0];
    const float dy = coords[src*3+1] - coords[dst*3+1];
    const float dz = coords[src*3+2] - coords[dst*3+2];
    const float dist = sqrtf(dx*dx + dy*dy + dz*dz + 1e-12f);
    #pragma unroll
    for (int k = 0; k < 16; k++) {
        const float t = 3.2f*dist - 1.0666666667f*(float)k;
        f[14+k] = f2bf(__expf(-t*t));
    }
    f[30] = f2bf(1.0f);
    f[31] = 0;

    const int slot = start[dst] + rank[e];
    short* out = featH + (size_t)slot*32;
    #pragma unroll
    for (int q = 0; q < 4; q++)
        *(short8*)&out[q*8] = *(short8*)&f[q*8];
}

// ---------------------------------------------------------------------------
// gather_mfma v7 (unchanged): 133 us, VALU-bound at its structural floor.
// ---------------------------------------------------------------------------
__global__ __launch_bounds__(256, 2) void gather_mfma(
    const short* __restrict__ featH1, const short* __restrict__ featH2,
    const int* __restrict__ start1, const int* __restrict__ start2,
    const short* __restrict__ WTH, const short* __restrict__ WTL,
    const float* __restrict__ ln_g, const float* __restrict__ ln_b,
    float* __restrict__ h1, float* __restrict__ h2)
{
    __shared__ short sWH[208*40];    // 16.6 KB, stride-40 (80B) rows
    __shared__ short sWL[208*40];    // 16.6 KB
    __shared__ float plane[4][216];

    const int tid = threadIdx.x;
    const int wv = tid >> 6, lane = tid & 63;
    const int arow = lane & 15, aq = lane >> 4;

    // stage W once per block (832 short8 per array)
    for (int f = tid; f < 832; f += 256) {
        const int d = f >> 2, cc = (f & 3) * 8;
        *(short8*)&sWH[d*40 + cc] = *(const short8*)&WTH[f*8];
        *(short8*)&sWL[d*40 + cc] = *(const short8*)&WTL[f*8];
    }
    __syncthreads();

    const int side = blockIdx.y;
    const short* feat = side ? featH2 : featH1;
    const int*  start = side ? start2 : start1;
    float* h = side ? h2 : h1;

    const int c0 = blockIdx.x*16 + wv*4;     // wave's first node (of 4)

    // hoist ln params (lane-mapped)
    const float g0 = ln_g[lane],      bb0 = ln_b[lane];
    const float g1 = ln_g[64+lane],   bb1 = ln_b[64+lane];
    const float g2 = ln_g[128+lane],  bb2 = ln_b[128+lane];
    const float g3 = (lane < 8) ? ln_g[192+lane] : 0.f;
    const float bb3 = (lane < 8) ? ln_b[192+lane] : 0.f;

    // 5 start values for the 4 nodes, one load, then readlane
    const int sidx = (lane < 5) ? lane : 4;
    const int sv = start[c0 + sidx];

    const int lb = arow*40 + aq*8;           // LDS element offset in a W tile

    #pragma unroll 1
    for (int ni = 0; ni < 4; ni++) {
        const int st = __builtin_amdgcn_readlane(sv, ni);
        const int en = __builtin_amdgcn_readlane(sv, ni + 1);
        const int dg = en - st;
        const int node = c0 + ni;
        const size_t hbase = (size_t)node * DH;

        // hoist h RMW loads (consumed at node end, hidden under tiles)
        const float hv0 = h[hbase + lane];
        const float hv1 = h[hbase + 64 + lane];
        const float hv2 = h[hbase + 128 + lane];
        const float hv3 = (lane < 8) ? h[hbase + 192 + lane] : 0.f;

        float colacc[13];
        #pragma unroll
        for (int nt = 0; nt < 13; nt++) colacc[nt] = 0.f;
        float musum = 0.f;

        short8 aC = *(const short8*)&feat[(size_t)(st + arow)*32 + aq*8];

        for (int t0 = 0; t0 < dg; t0 += 16) {
            // prefetch next tile; overshoot lands in next node's rows or the
            // zeroed 16-row pad (start[BN]=EE sentinel) — discarded if unused
            const short8 aN = *(const short8*)&feat[(size_t)(st + t0 + 16 + arow)*32 + aq*8];

            f32x4 acc[13];
            #pragma unroll
            for (int nt = 0; nt < 13; nt++) {
                const short8 whv = *(const short8*)&sWH[nt*640 + lb];
                const short8 wlv = *(const short8*)&sWL[nt*640 + lb];
                f32x4 z = (f32x4){0.f,0.f,0.f,0.f};
                z = __builtin_amdgcn_mfma_f32_16x16x32_bf16(aC, whv, z, 0, 0, 0);
                z = __builtin_amdgcn_mfma_f32_16x16x32_bf16(aC, wlv, z, 0, 0, 0);
                acc[nt] = z;
            }
            // relu + per-row (per-edge) stats; row = t0 + aq*4 + r
            float sr[4] = {0.f,0.f,0.f,0.f}, s2r[4] = {0.f,0.f,0.f,0.f};
            #pragma unroll
            for (int nt = 0; nt < 13; nt++) {
                #pragma unroll
                for (int r = 0; r < 4; r++) {
                    const float v = fmaxf(acc[nt][r], 0.f);
                    acc[nt][r] = v;
                    sr[r] += v; s2r[r] += v*v;
                }
            }
            // 16-lane sum across arow via DPP (VALU-only)
            #pragma unroll
            for (int r = 0; r < 4; r++) {
                sr[r]  = dpp16_sum(sr[r]);
                s2r[r] = dpp16_sum(s2r[r]);
            }
            #pragma unroll
            for (int r = 0; r < 4; r++) {
                const bool valid = (t0 + aq*4 + r) < dg;
                const float mean = sr[r] * (1.0f/DH);
                const float var  = s2r[r] * (1.0f/DH) - mean*mean;
                const float rs   = rsqrtf(var + 1e-5f);
                const float rstd = valid ? rs : 0.f;
                musum += valid ? mean*rs : 0.f;
                #pragma unroll
                for (int nt = 0; nt < 13; nt++)
                    colacc[nt] += rstd*acc[nt][r];
            }
            aC = aN;
        }

        // reduce over the 4 aq groups (rows partition)
        #pragma unroll
        for (int nt = 0; nt < 13; nt++) {
            colacc[nt] += __shfl_xor(colacc[nt], 16, 64);
            colacc[nt] += __shfl_xor(colacc[nt], 32, 64);
        }
        musum += __shfl_xor(musum, 16, 64);
        musum += __shfl_xor(musum, 32, 64);

        if (aq == 0) {
            #pragma unroll
            for (int nt = 0; nt < 13; nt++)
                plane[wv][nt*16 + arow] = colacc[nt];
        }
        // wave-internal LDS producer/consumer: DS pipe is in-order per wave —
        // no barrier (and the next node's writes issue after these reads)

        const float dgf = (float)dg;
        h[hbase + lane]       = hv0 + g0*(plane[wv][lane]     - musum) + dgf*bb0;
        h[hbase + 64 + lane]  = hv1 + g1*(plane[wv][64+lane]  - musum) + dgf*bb1;
        h[hbase + 128 + lane] = hv2 + g2*(plane[wv][128+lane] - musum) + dgf*bb2;
        if (lane < 8)
            h[hbase + 192 + lane] = hv3 + g3*(plane[wv][192+lane] - musum) + dgf*bb3;
    }
}

// ---------------------------------------------------------------------------
// cvt (per half): h fp32 -> hb hi/lo [16384][224] rows + hbT hi/lo [32][224][512]
// ---------------------------------------------------------------------------
__global__ __launch_bounds__(256) void cvt_kernel(
    const float* __restrict__ h1, const float* __restrict__ h2, const int half,
    short* __restrict__ hbH1, short* __restrict__ hbL1,
    short* __restrict__ hbH2, short* __restrict__ hbL2,
    short* __restrict__ hTH1, short* __restrict__ hTL1,
    short* __restrict__ hTH2, short* __restrict__ hTL2)
{
    const int side = blockIdx.y;
    const float* h = side ? h2 : h1;
    short* hbH = side ? hbH2 : hbH1;
    short* hbL = side ? hbL2 : hbL1;
    short* hTH = side ? hTH2 : hTH1;
    short* hTL = side ? hTL2 : hTL1;

    const int nl0 = blockIdx.x * 64;          // local node
    const int bl = nl0 >> 9, m0 = nl0 & 511;
    const int ng0 = half*HBN + nl0;

    __shared__ short tH[64][226];
    __shared__ short tL[64][226];
    const int tid = threadIdx.x;
    for (int i = tid; i < 64*224; i += 256) {
        const int r = i / 224, c = i - r*224;
        const float v = (c < DH) ? h[(size_t)(ng0+r)*DH + c] : 0.f;
        const short hi = f2bf(v);
        const short lo = f2bf(v - bf2f(hi));
        tH[r][c] = hi; tL[r][c] = lo;
        hbH[(size_t)(nl0+r)*224 + c] = hi;
        hbL[(size_t)(nl0+r)*224 + c] = lo;
    }
    __syncthreads();
    for (int i = tid; i < 224*64; i += 256) {
        const int c = i >> 6, m = i & 63;
        const size_t o = ((size_t)bl*224 + c)*NN + m0 + m;
        hTH[o] = tH[m][c];
        hTL[o] = tL[m][c];
    }
}

// ---------------------------------------------------------------------------
// Fused attention v8 (unchanged): 64 Q-rows/block, 512 blocks x 512 thr,
// both dirs in one dispatch, XCD-partitioned.
// ---------------------------------------------------------------------------
__global__ __launch_bounds__(512, 2) void attn_kernel(
    const short* __restrict__ hbH1, const short* __restrict__ hbL1,
    const short* __restrict__ hbH2, const short* __restrict__ hbL2,
    const short* __restrict__ hTH1, const short* __restrict__ hTL1,
    const short* __restrict__ hTH2, const short* __restrict__ hTL2,
    short* __restrict__ cb1, short* __restrict__ cb2)
{
    const int id  = blockIdx.x;                // 0..511
    const int xcd = id & 7, m = id >> 3;       // m 0..63
    const int b2  = m >> 4;                    // 0..3
    const int dir = (m >> 3) & 1;
    const int qb  = m & 7;
    const int b   = xcd*4 + b2;                // half-local batch 0..31
    const int q0  = qb << 6;                   // 64 q-rows

    const short *Qh, *Ql, *Kh, *Kl, *Vh, *Vl;
    short* cb;
    if (dir == 0) {
        Qh = hbH1 + (size_t)b*NN*224;  Ql = hbL1 + (size_t)b*NN*224;
        Kh = hbH2 + (size_t)b*NN*224;  Kl = hbL2 + (size_t)b*NN*224;
        Vh = hTH2 + (size_t)b*224*NN;  Vl = hTL2 + (size_t)b*224*NN;
        cb = cb1;
    } else {
        Qh = hbH2 + (size_t)b*NN*224;  Ql = hbL2 + (size_t)b*NN*224;
        Kh = hbH1 + (size_t)b*NN*224;  Kl = hbL1 + (size_t)b*NN*224;
        Vh = hTH1 + (size_t)b*224*NN;  Vl = hTL1 + (size_t)b*224*NN;
        cb = cb2;
    }

    __shared__ short smem[64*520];            // 65 KB: pb, aliases sQ
    short* sQh = smem;                        // [64][232] = 14848 shorts
    short* sQl = smem + 14848;                // [64][232]
    short* pb  = smem;                        // [64][520]
    __shared__ float sm_[8][64];
    __shared__ float ss_[8][64];

    const int tid = threadIdx.x;
    const int wv = tid >> 6, lane = tid & 63;
    const int arow = lane & 15, aq = lane >> 4;

    // stage Q (64 rows x 224, hi/lo) cooperatively
    for (int i = tid; i < 1792; i += 512) {
        const int rr = i / 28, c = (i - rr*28) * 8;
        *(short8*)&sQh[rr*232 + c] = *(const short8*)&Qh[(size_t)(q0 + rr)*224 + c];
        *(short8*)&sQl[rr*232 + c] = *(const short8*)&Ql[(size_t)(q0 + rr)*224 + c];
    }
    __syncthreads();

    f32x4 acc[4][4];
    #pragma unroll
    for (int g = 0; g < 4; g++)
        #pragma unroll
        for (int t = 0; t < 4; t++) acc[g][t] = (f32x4){0.f,0.f,0.f,0.f};

    const int qb_off = arow*232 + aq*8;
    #pragma unroll 1
    for (int k = 0; k < 7; k++) {
        short8 qh[4], ql[4];
        #pragma unroll
        for (int g = 0; g < 4; g++) {
            qh[g] = *(const short8*)&sQh[qb_off + g*16*232 + k*32];
            ql[g] = *(const short8*)&sQl[qb_off + g*16*232 + k*32];
        }
        #pragma unroll
        for (int t = 0; t < 4; t++) {
            const size_t kb = (size_t)((wv*4 + t)*16 + arow)*224 + k*32 + aq*8;
            const short8 bh = *(const short8*)&Kh[kb];
            const short8 bl = *(const short8*)&Kl[kb];
            #pragma unroll
            for (int g = 0; g < 4; g++) {
                acc[g][t] = __builtin_amdgcn_mfma_f32_16x16x32_bf16(qh[g], bh, acc[g][t], 0, 0, 0);
                acc[g][t] = __builtin_amdgcn_mfma_f32_16x16x32_bf16(qh[g], bl, acc[g][t], 0, 0, 0);
                acc[g][t] = __builtin_amdgcn_mfma_f32_16x16x32_bf16(ql[g], bh, acc[g][t], 0, 0, 0);
            }
        }
    }

    #pragma unroll
    for (int g = 0; g < 4; g++) {
        #pragma unroll
        for (int r2 = 0; r2 < 4; r2++) {
            float mx = -1e30f;
            #pragma unroll
            for (int t = 0; t < 4; t++) {
                acc[g][t][r2] *= T_SCALE;
                mx = fmaxf(mx, acc[g][t][r2]);
            }
            mx = fmaxf(mx, __shfl_xor(mx, 1, 64));
            mx = fmaxf(mx, __shfl_xor(mx, 2, 64));
            mx = fmaxf(mx, __shfl_xor(mx, 4, 64));
            mx = fmaxf(mx, __shfl_xor(mx, 8, 64));
            if (arow == 0) sm_[wv][g*16 + aq*4 + r2] = mx;
        }
    }
    __syncthreads();
    #pragma unroll
    for (int g = 0; g < 4; g++) {
        #pragma unroll
        for (int r2 = 0; r2 < 4; r2++) {
            const int row = g*16 + aq*4 + r2;
            float M = sm_[0][row];
            #pragma unroll
            for (int w = 1; w < 8; w++) M = fmaxf(M, sm_[w][row]);
            float s = 0.f;
            #pragma unroll
            for (int t = 0; t < 4; t++) {
                const float e = __expf(acc[g][t][r2] - M);
                acc[g][t][r2] = e;
                s += e;
            }
            s += __shfl_xor(s, 1, 64);
            s += __shfl_xor(s, 2, 64);
            s += __shfl_xor(s, 4, 64);
            s += __shfl_xor(s, 8, 64);
            if (arow == 0) ss_[wv][row] = s;
        }
    }
    __syncthreads();
    // all waves are past the QK phase (2 barriers above) — safe to overwrite sQ
    #pragma unroll
    for (int g = 0; g < 4; g++) {
        #pragma unroll
        for (int r2 = 0; r2 < 4; r2++) {
            const int row = g*16 + aq*4 + r2;
            float s = ss_[0][row];
            #pragma unroll
            for (int w = 1; w < 8; w++) s += ss_[w][row];
            const float iv = 1.0f / s;
            #pragma unroll
            for (int t = 0; t < 4; t++) {
                const int col = (wv*4 + t)*16 + arow;
                pb[row*520 + col] = f2bf(acc[g][t][r2] * iv);
            }
        }
    }
    __syncthreads();

    const int nbase = (wv < 5) ? 2*wv : 10 + (wv - 5);
    const int ncnt  = (wv < 5) ? 2 : 1;
    f32x4 pacc[4][2];
    #pragma unroll
    for (int g = 0; g < 4; g++)
        #pragma unroll
        for (int t = 0; t < 2; t++) pacc[g][t] = (f32x4){0.f,0.f,0.f,0.f};

    for (int k0 = 0; k0 < NN; k0 += 32) {
        short8 a[4];
        #pragma unroll
        for (int g = 0; g < 4; g++)
            a[g] = *(const short8*)&pb[(g*16 + arow)*520 + k0 + aq*8];
        #pragma unroll
        for (int t = 0; t < 2; t++) {
            if (t < ncnt) {
                const size_t vb = (size_t)((nbase+t)*16 + arow)*NN + k0 + aq*8;
                const short8 bh = *(const short8*)&Vh[vb];
                const short8 bl = *(const short8*)&Vl[vb];
                #pragma unroll
                for (int g = 0; g < 4; g++) {
                    pacc[g][t] = __builtin_amdgcn_mfma_f32_16x16x32_bf16(a[g], bh, pacc[g][t], 0, 0, 0);
                    pacc[g][t] = __builtin_amdgcn_mfma_f32_16x16x32_bf16(a[g], bl, pacc[g][t], 0, 0, 0);
                }
            }
        }
    }

    #pragma unroll
    for (int t = 0; t < 2; t++) {
        if (t < ncnt) {
            const int col = (nbase+t)*16 + arow;
            #pragma unroll
            for (int g = 0; g < 4; g++) {
                #pragma unroll
                for (int r2 = 0; r2 < 4; r2++) {
                    const int row = q0 + g*16 + aq*4 + r2;
                    const short v = (col < DH) ? f2bf(pacc[g][t][r2]) : (short)0;
                    cb[((size_t)b*NN + row)*224 + col] = v;
                }
            }
        }
    }
    if (wv == 7) {
        const int col = 208 + arow;
        #pragma unroll
        for (int g = 0; g < 4; g++) {
            #pragma unroll
            for (int r2 = 0; r2 < 4; r2++) {
                const int row = q0 + g*16 + aq*4 + r2;
                cb[((size_t)b*NN + row)*224 + col] = 0;
            }
        }
    }
}

// ---------------------------------------------------------------------------
// down v3 (512 thr, 128 nodes/block): As staging dropped (A-fragments read
// directly from global — zero redundancy, same 16-row x 16B pattern as
// attn's K reads) and W tile double-buffered -> ONE barrier per k-step
// (14 vs 28). MFMA order per step/t unchanged -> bit-identical numerics.
// LDS: 2x(16.6+16.6) + part = ~67.4 KB.
// ---------------------------------------------------------------------------
__global__ __launch_bounds__(512, 2) void down_mfma(
    const short* __restrict__ hbH1, const short* __restrict__ hbH2,
    const short* __restrict__ cb1, const short* __restrict__ cb2,
    const int* __restrict__ deg1, const int* __restrict__ deg2,
    const short* __restrict__ WbTH, const short* __restrict__ WbTL,
    const float* __restrict__ degree_table,
    float* __restrict__ hsg1, float* __restrict__ hsg2, const int half)
{
    const int side = blockIdx.y;
    const short* X0 = side ? hbH2 : hbH1;
    const short* X1 = side ? cb2 : cb1;
    const int*   dgp = side ? deg2 : deg1;
    float* hsg = side ? hsg2 : hsg1;

    const int nl0 = blockIdx.x * 128;
    const int ng0 = half*HBN + nl0;
    const int b = ng0 >> 9;

    __shared__ short BsH[2][208*40];
    __shared__ short BsL[2][208*40];
    __shared__ float part[208];

    const int tid = threadIdx.x;
    const int wv = tid >> 6, lane = tid & 63;
    const int arow = lane & 15, aq = lane >> 4;

    if (tid < 208) part[tid] = 0.f;

    f32x4 acc[13];
    #pragma unroll
    for (int t = 0; t < 13; t++) acc[t] = (f32x4){0.f,0.f,0.f,0.f};

    // stage W tile for step s into buffer buf
    auto stage = [&](int buf, int s) {
        const int kkg = (s / 7)*224 + (s % 7)*32;
        #pragma unroll
        for (int pass = 0; pass < 2; pass++) {
            const int f = pass*512 + tid;
            if (f < 832) {
                const int d = f >> 2, cc = (f & 3) * 8;
                *(short8*)&BsH[buf][d*40 + cc] = *(const short8*)&WbTH[(size_t)d*448 + kkg + cc];
                *(short8*)&BsL[buf][d*40 + cc] = *(const short8*)&WbTL[(size_t)d*448 + kkg + cc];
            }
        }
    };

    stage(0, 0);
    __syncthreads();

    #pragma unroll 1
    for (int s = 0; s < 14; s++) {
        const int cur = s & 1;
        if (s + 1 < 14) stage(cur ^ 1, s + 1);   // prefetch next W tile
        const int phase = s / 7, k0 = (s % 7)*32;
        const short* X = phase ? X1 : X0;
        const short8 a = *(const short8*)&X[(size_t)(nl0 + 16*wv + arow)*224 + k0 + aq*8];
        #pragma unroll
        for (int t = 0; t < 13; t++) {
            const short8 bh = *(const short8*)&BsH[cur][(t*16 + arow)*40 + aq*8];
            const short8 bl = *(const short8*)&BsL[cur][(t*16 + arow)*40 + aq*8];
            acc[t] = __builtin_amdgcn_mfma_f32_16x16x32_bf16(a, bh, acc[t], 0, 0, 0);
            acc[t] = __builtin_amdgcn_mfma_f32_16x16x32_bf16(a, bl, acc[t], 0, 0, 0);
        }
        __syncthreads();   // orders: my nxt-writes & cur-reads vs next iter
    }

    int dgc[4];
    #pragma unroll
    for (int r = 0; r < 4; r++) {
        int d = dgp[ng0 + 16*wv + aq*4 + r];
        dgc[r] = d > 199 ? 199 : d;
    }
    #pragma unroll
    for (int nt = 0; nt < 13; nt++) {
        const int col = nt*16 + arow;
        float s = 0.f;
        if (col < DH) {
            #pragma unroll
            for (int r = 0; r < 4; r++)
                s += fmaxf(acc[nt][r], 0.f) + degree_table[dgc[r]*DH + col];
        }
        s += __shfl_xor(s, 16, 64);
        s += __shfl_xor(s, 32, 64);
        if (lane < 16 && col < DH) atomicAdd(&part[col], s);
    }
    __syncthreads();
    if (tid < DH) unsafeAtomicAdd(&hsg[b*206 + tid], part[tid] * (1.0f/512.0f));
}

// ---------------------------------------------------------------------------
// Kernel 7: final MLP v2 — float4 broadcast reads of x/y1/y2.
// ---------------------------------------------------------------------------
__global__ __launch_bounds__(256) void mlp_kernel(
    const float* __restrict__ hsg1, const float* __restrict__ hsg2,
    const float* __restrict__ i1, const float* __restrict__ i2,
    const float* __restrict__ W_f1, const float* __restrict__ b_f1,
    const float* __restrict__ W_f2, const float* __restrict__ b_f2,
    const float* __restrict__ W_f3, const float* __restrict__ b_f3,
    const float* __restrict__ W_f4, const float* __restrict__ b_f4,
    float* __restrict__ out)
{
    const int b = blockIdx.x;
    __shared__ float x[620];
    __shared__ float y1[400];
    __shared__ float y2[200];
    __shared__ float y3[100];
    __shared__ float red[256];
    const int tid = threadIdx.x;

    // interaction means (folded inter_kernel); y2 used as scratch pre-layer2
    if (tid < 192) {
        const int j = tid % 6, seg = tid / 6;
        float s1 = 0.f, s2 = 0.f;
        for (int n = seg*16; n < seg*16 + 16; n++) {
            s1 += i1[(size_t)b*NN*DI + n*DI + j];
            s2 += i2[(size_t)b*NN*DI + n*DI + j];
        }
        red[tid] = s1;
        y2[tid] = s2;
    }
    __syncthreads();
    if (tid < 206) {
        float a, bb;
        if (tid < 200) {
            a = hsg1[b*206 + tid]; bb = hsg2[b*206 + tid];
        } else {
            const int j = tid - 200;
            float t1 = 0.f, t2 = 0.f;
            for (int sg = 0; sg < 32; sg++) { t1 += red[sg*6 + j]; t2 += y2[sg*6 + j]; }
            a = t1 * (1.0f/512.0f); bb = t2 * (1.0f/512.0f);
        }
        x[tid] = a; x[206 + tid] = bb; x[412 + tid] = a - bb;
    }
    __syncthreads();
    for (int c = tid; c < 400; c += 256) {
        float acc = b_f1[c];
        for (int k4 = 0; k4 < 154; k4++) {
            const float4 xv = *(const float4*)&x[k4*4];
            const int k = k4*4;
            acc += xv.x*W_f1[(size_t)(k+0)*400 + c];
            acc += xv.y*W_f1[(size_t)(k+1)*400 + c];
            acc += xv.z*W_f1[(size_t)(k+2)*400 + c];
            acc += xv.w*W_f1[(size_t)(k+3)*400 + c];
        }
        acc += x[616]*W_f1[(size_t)616*400 + c];
        acc += x[617]*W_f1[(size_t)617*400 + c];
        y1[c] = fmaxf(acc, 0.0f);
    }
    __syncthreads();
    if (tid < 200) {
        float acc = b_f2[tid];
        for (int k4 = 0; k4 < 100; k4++) {
            const float4 yv = *(const float4*)&y1[k4*4];
            const int k = k4*4;
            acc += yv.x*W_f2[(k+0)*200 + tid];
            acc += yv.y*W_f2[(k+1)*200 + tid];
            acc += yv.z*W_f2[(k+2)*200 + tid];
            acc += yv.w*W_f2[(k+3)*200 + tid];
        }
        y2[tid] = fmaxf(acc, 0.0f);
    }
    __syncthreads();
    if (tid < 100) {
        float acc = b_f3[tid];
        for (int k4 = 0; k4 < 50; k4++) {
            const float4 yv = *(const float4*)&y2[k4*4];
            const int k = k4*4;
            acc += yv.x*W_f3[(k+0)*100 + tid];
            acc += yv.y*W_f3[(k+1)*100 + tid];
            acc += yv.z*W_f3[(k+2)*100 + tid];
            acc += yv.w*W_f3[(k+3)*100 + tid];
        }
        y3[tid] = fmaxf(acc, 0.0f);
    }
    __syncthreads();
    red[tid] = (tid < 100) ? y3[tid]*W_f4[tid] : 0.0f;
    __syncthreads();
    for (int s = 128; s > 0; s >>= 1) {
        if (tid < s) red[tid] += red[tid + s];
        __syncthreads();
    }
    if (tid == 0) out[b] = red[0] + b_f4[0];
}

// ---------------------------------------------------------------------------
extern "C" void kernel_launch(void* const* d_in, const int* in_sizes, int n_in,
                              void* d_out, int out_size, void* d_ws, size_t ws_size,
                              hipStream_t stream)
{
    const float* atom1  = (const float*)d_in[0];
    const float* atom2  = (const float*)d_in[1];
    const float* coords1= (const float*)d_in[2];
    const float* coords2= (const float*)d_in[3];
    const float* efeat1 = (const float*)d_in[4];
    const float* efeat2 = (const float*)d_in[5];
    const float* inter1 = (const float*)d_in[6];
    const float* inter2 = (const float*)d_in[7];
    const int*   esrc1  = (const int*)d_in[8];
    const int*   edst1  = (const int*)d_in[9];
    const int*   esrc2  = (const int*)d_in[10];
    const int*   edst2  = (const int*)d_in[11];
    const float* W_atom = (const float*)d_in[12];
    const float* W_edge = (const float*)d_in[13];
    const float* W_rbf  = (const float*)d_in[14];
    const float* b_rbf  = (const float*)d_in[15];
    const float* ln_g   = (const float*)d_in[16];
    const float* ln_b   = (const float*)d_in[17];
    const float* W_down = (const float*)d_in[18];
    const float* deg_tab= (const float*)d_in[19];
    const float* W_f1   = (const float*)d_in[20];
    const float* b_f1   = (const float*)d_in[21];
    const float* W_f2   = (const float*)d_in[22];
    const float* b_f2   = (const float*)d_in[23];
    const float* W_f3   = (const float*)d_in[24];
    const float* b_f3   = (const float*)d_in[25];
    const float* W_f4   = (const float*)d_in[26];
    const float* b_f4   = (const float*)d_in[27];
    float* out = (float*)d_out;

    // ---- workspace layout (~133 MB)
    float* ws = (float*)d_ws;
    const size_t HSZ = (size_t)BN*DH;              // per-side h floats
    float* h1  = ws;
    float* h2  = h1 + HSZ;
    // pool: max(feat 2*(EE+16)*32 shorts, bf16 pool 10*HB shorts)
    short* pool = (short*)(h2 + HSZ);
    const size_t FSZ = (size_t)(EE+16)*32;
    short* featH1 = pool;
    short* featH2 = featH1 + FSZ;
    const size_t HB = (size_t)32*NN*224;           // 3,670,016 shorts
    short* hbH1 = pool;           short* hbL1 = hbH1 + HB;
    short* hbH2 = hbL1 + HB;      short* hbL2 = hbH2 + HB;
    short* hTH1 = hbL2 + HB;      short* hTL1 = hTH1 + HB;
    short* hTH2 = hTL1 + HB;      short* hTL2 = hTH2 + HB;
    short* cb1  = hTL2 + HB;      short* cb2  = cb1 + HB;
    size_t pool_sz = 2*FSZ > 10*HB ? 2*FSZ : 10*HB;
    short* after = pool + pool_sz;
    short* WTH = after;                            // [208][32]
    short* WTL = WTH + 208*32;
    short* WbTH = WTL + 208*32;                    // [208][448]
    short* WbTL = WbTH + 208*448;
    float* hsg1 = (float*)(WbTL + 208*448);
    float* hsg2 = hsg1 + (size_t)BB*206;
    int* deg1 = (int*)(hsg2 + (size_t)BB*206);
    int* deg2 = deg1 + BN;
    int* start1 = deg2 + BN;                       // BN+1 entries
    int* start2 = start1 + (BN+1);
    int* cursor1 = start2 + (BN+1);                // unused (kept for layout)
    int* cursor2 = cursor1 + BN;
    int* rank1 = cursor2 + BN;
    int* rank2 = rank1 + EE;

    hipMemsetAsync(deg1, 0, 2*(size_t)BN*sizeof(int), stream);
    hipMemsetAsync(hsg1, 0, 2*(size_t)BB*206*sizeof(float), stream);

    // fused: hist FIRST, then node(16/block) + prep_w + prep_wt(+featpad)
    prologue_kernel<<<6536, 256, 0, stream>>>(
        atom1, atom2, W_atom, ln_g, ln_b, h1, h2,
        edst1, edst2, deg1, deg2, rank1, rank2,
        W_edge, W_rbf, b_rbf, WTH, WTL, featH1, featH2,
        W_down, WbTH, WbTL);

    scan_kernel<<<2, 1024, 0, stream>>>(deg1, deg2, start1, start2);

    featgen_kernel<<<dim3(EE/256, 2), 256, 0, stream>>>(
        efeat1, efeat2, esrc1, esrc2, edst1, edst2, coords1, coords2,
        rank1, rank2, start1, start2, featH1, featH2);

    gather_mfma<<<dim3(BN/16, 2), 256, 0, stream>>>(
        featH1, featH2, start1, start2, WTH, WTL, ln_g, ln_b, h1, h2);

    for (int half = 0; half < 2; half++) {
        cvt_kernel<<<dim3(HBN/64, 2), 256, 0, stream>>>(
            h1, h2, half, hbH1, hbL1, hbH2, hbL2, hTH1, hTL1, hTH2, hTL2);
        // both directions in one dispatch, 64 q-rows per block
        attn_kernel<<<512, 512, 0, stream>>>(
            hbH1, hbL1, hbH2, hbL2, hTH1, hTL1, hTH2, hTL2, cb1, cb2);
        down_mfma<<<dim3(HBN/128, 2), 512, 0, stream>>>(
            hbH1, hbH2, cb1, cb2, deg1, deg2, WbTH, WbTL, deg_tab,
            hsg1, hsg2, half);
    }

    mlp_kernel<<<BB, 256, 0, stream>>>(
        hsg1, hsg2, inter1, inter2,
        W_f1, b_f1, W_f2, b_f2, W_f3, b_f3, W_f4, b_f4, out);
}